// Round 5
// baseline (6922.232 us; speedup 1.0000x reference)
//
#include <hip/hip_runtime.h>
#include <hip/hip_bf16.h>
#include <math.h>

#define B_   128
#define L_   16
#define E_   768
#define D_   384
#define H_   12
#define HD_  64
#define NL_  6
#define SEQ_ 12
#define LN_EPS 0.001f
#define WLS   7077888               // bf16 elems per layer weight pack
#define BQS   2304

typedef __attribute__((ext_vector_type(8))) short bf16x8;
typedef __attribute__((ext_vector_type(4))) float f32x4;
typedef unsigned long long u64;

#define GLOAD_LDS16(g, l) \
    __builtin_amdgcn_global_load_lds((__attribute__((address_space(1))) const void*)(g), \
                                     (__attribute__((address_space(3))) void*)(l), 16, 0, 0)

// ---------------- XS = cos(X*omega + phase) ----------------
__global__ __launch_bounds__(256) void k_xs(const float* __restrict__ X,
                                            const float* __restrict__ om,
                                            const float* __restrict__ ph,
                                            float* __restrict__ XS) {
    int i = blockIdx.x * 256 + threadIdx.x;
    if (i >= B_*L_*3*D_) return;
    int d  = i % D_;
    int ch = (i / D_) % 3;
    int bt = i / (3*D_);
    XS[i] = cosf(X[bt*3 + ch] * om[ch*D_ + d] + ph[ch*D_ + d]);
}

// ---------------- build x0 for CL lidx starting at cb ----------------
__global__ __launch_bounds__(256) void k_x0(const float* __restrict__ XS,
                                            const float* __restrict__ targets,
                                            const int* __restrict__ perms,
                                            float* __restrict__ x, int cb, int ntok) {
    int i = blockIdx.x * 256 + threadIdx.x;
    if (i >= ntok*E_) return;
    int e   = i % E_;
    int tok = i / E_;
    int s   = tok % SEQ_;
    int bi  = (tok / SEQ_) % B_;
    int c   = tok / (SEQ_*B_);
    int cl  = cb + c;
    int lidx = cl + 1;
    int pb  = perms[cl*B_ + bi];
    float val;
    if (s < 3) {
        int t = (e < D_) ? (L_ - lidx) : (L_ - lidx - 1);
        int d = (e < D_) ? e : (e - D_);
        val = XS[((pb*L_ + t)*3 + s)*D_ + d];
    } else if (s < 6) {
        int t = (17 - lidx) & 15;
        val = targets[(pb*L_ + t)*3 + (s - 3)];
    } else {
        val = (float)(L_ - lidx);
    }
    x[i] = val;
}

// ---------------- LayerNorm: one wave per token, no barriers ----------------
__global__ __launch_bounds__(256) void k_ln(const float* __restrict__ x,
                                            const float* __restrict__ g,
                                            const float* __restrict__ b,
                                            __hip_bfloat16* __restrict__ h) {
    int gi = blockIdx.x * 256 + threadIdx.x;
    int tok = gi >> 6, lane = gi & 63;
    const float4* xr = (const float4*)(x + (size_t)tok * E_);
    float4 v0 = xr[lane], v1 = xr[lane + 64], v2 = xr[lane + 128];
    float s = v0.x+v0.y+v0.z+v0.w + v1.x+v1.y+v1.z+v1.w + v2.x+v2.y+v2.z+v2.w;
    #pragma unroll
    for (int o = 32; o > 0; o >>= 1) s += __shfl_xor(s, o, 64);
    float mu = s * (1.0f / E_);
    v0.x-=mu; v0.y-=mu; v0.z-=mu; v0.w-=mu;
    v1.x-=mu; v1.y-=mu; v1.z-=mu; v1.w-=mu;
    v2.x-=mu; v2.y-=mu; v2.z-=mu; v2.w-=mu;
    float q = v0.x*v0.x+v0.y*v0.y+v0.z*v0.z+v0.w*v0.w
            + v1.x*v1.x+v1.y*v1.y+v1.z*v1.z+v1.w*v1.w
            + v2.x*v2.x+v2.y*v2.y+v2.z*v2.z+v2.w*v2.w;
    #pragma unroll
    for (int o = 32; o > 0; o >>= 1) q += __shfl_xor(q, o, 64);
    float rstd = rsqrtf(q * (1.0f / E_) + LN_EPS);
    const float4* g4 = (const float4*)g;
    const float4* b4 = (const float4*)b;
    ushort4* h4 = (ushort4*)(h + (size_t)tok * E_);
    #pragma unroll
    for (int k = 0; k < 3; k++) {
        float4 v = (k == 0) ? v0 : (k == 1) ? v1 : v2;
        float4 gg = g4[lane + k*64], bb = b4[lane + k*64];
        ushort4 o;
        o.x = __bfloat16_as_ushort(__float2bfloat16(v.x * rstd * gg.x + bb.x));
        o.y = __bfloat16_as_ushort(__float2bfloat16(v.y * rstd * gg.y + bb.y));
        o.z = __bfloat16_as_ushort(__float2bfloat16(v.z * rstd * gg.z + bb.z));
        o.w = __bfloat16_as_ushort(__float2bfloat16(v.w * rstd * gg.w + bb.w));
        h4[lane + k*64] = o;
    }
}

// ---------------- weight transpose+convert fp32[K][N] -> bf16[N][K], nl layers ----------------
__global__ __launch_bounds__(256) void k_cvt(const float* __restrict__ Wq,
                                             const float* __restrict__ Wk,
                                             const float* __restrict__ Wv,
                                             const float* __restrict__ Wo,
                                             const float* __restrict__ W1,
                                             const float* __restrict__ W2,
                                             const float* __restrict__ bq,
                                             const float* __restrict__ bk,
                                             const float* __restrict__ bv,
                                             __hip_bfloat16* __restrict__ wl0,
                                             float* __restrict__ bqkv0, int lbase) {
    int bid = blockIdx.x;
    int l   = lbase + bid / 6913;
    bid %= 6913;
    __hip_bfloat16* wl = wl0 + (size_t)(l - lbase) * WLS;
    float* bqkv = bqkv0 + (l - lbase) * BQS;
    int tid = threadIdx.x;
    if (bid == 6912) {
        for (int i = tid; i < 2304; i += 256) {
            float v = (i < 768) ? bq[l*768 + i] : (i < 1536) ? bk[l*768 + i - 768]
                                                             : bv[l*768 + i - 1536];
            bqkv[i] = v;
        }
        return;
    }
    const float* src; __hip_bfloat16* dst; int K, N, ti, tj;
    if (bid < 1728) {
        int part = bid / 576, idx = bid % 576;
        const float* srcs[3] = {Wq, Wk, Wv};
        src = srcs[part] + (size_t)l*768*768; dst = wl + (size_t)part*768*768;
        K = 768; N = 768; tj = idx % 24; ti = idx / 24;
    } else if (bid < 2304) {
        int idx = bid - 1728;
        src = Wo + (size_t)l*768*768; dst = wl + 1769472;
        K = 768; N = 768; tj = idx % 24; ti = idx / 24;
    } else if (bid < 4608) {
        int idx = bid - 2304;
        src = W1 + (size_t)l*768*3072; dst = wl + 2359296;
        K = 768; N = 3072; tj = idx % 96; ti = idx / 96;
    } else {
        int idx = bid - 4608;
        src = W2 + (size_t)l*3072*768; dst = wl + 4718592;
        K = 3072; N = 768; tj = idx % 24; ti = idx / 24;
    }
    __shared__ float tbuf[32][33];
    int tx = tid & 31, ty = tid >> 5;
    #pragma unroll
    for (int p = 0; p < 4; p++) {
        int k = ti*32 + ty + p*8, n = tj*32 + tx;
        tbuf[ty + p*8][tx] = src[(size_t)k*N + n];
    }
    __syncthreads();
    #pragma unroll
    for (int p = 0; p < 4; p++) {
        int n = tj*32 + ty + p*8, k = ti*32 + tx;
        dst[(size_t)n*K + k] = __float2bfloat16(tbuf[tx][ty + p*8]);
    }
}

// ---------------- bf16 MFMA GEMM: C(+)= A[M][K] @ Bt[N][K]^T, tile 128x128 ----------------
// A row stride == K. Bt row stride == ldb (ldb >= K slice). flags: 1=bf16 out, 2=fp32 +=, 4=relu
__global__ __launch_bounds__(256) void k_gemm(const __hip_bfloat16* __restrict__ A,
                                              const __hip_bfloat16* __restrict__ Bt,
                                              const float* __restrict__ bias,
                                              void* __restrict__ Cp,
                                              int K, int ldb, int ldc, int flags) {
    __shared__ __align__(16) char smem[16384];
    char* As = smem;
    char* Bs = smem + 8192;
    int tid = threadIdx.x;
    int lane = tid & 63;
    int w = tid >> 6;
    int wm = (w >> 1) * 64, wn = (w & 1) * 64;
    int m0 = blockIdx.y * 128, n0 = blockIdx.x * 128;

    int u1 = tid, u2 = tid + 256;
    int r1 = u1 >> 2, kg1 = ((u1 & 3) ^ ((r1 >> 1) & 3)) * 8;
    int r2 = u2 >> 2, kg2 = ((u2 & 3) ^ ((r2 >> 1) & 3)) * 8;

    f32x4 acc[4][4] = {};
    int fr = lane & 15, fkg = lane >> 4;

    for (int k0 = 0; k0 < K; k0 += 32) {
        GLOAD_LDS16(A  + (size_t)(m0 + r1) * K   + k0 + kg1, As + u1 * 16);
        GLOAD_LDS16(A  + (size_t)(m0 + r2) * K   + k0 + kg2, As + u2 * 16);
        GLOAD_LDS16(Bt + (size_t)(n0 + r1) * ldb + k0 + kg1, Bs + u1 * 16);
        GLOAD_LDS16(Bt + (size_t)(n0 + r2) * ldb + k0 + kg2, Bs + u2 * 16);
        __syncthreads();
        bf16x8 a[4], b[4];
        #pragma unroll
        for (int i = 0; i < 4; i++) {
            int m = wm + i*16 + fr;
            a[i] = *(const bf16x8*)(As + m*64 + ((fkg ^ ((m >> 1) & 3)) * 16));
            int n = wn + i*16 + fr;
            b[i] = *(const bf16x8*)(Bs + n*64 + ((fkg ^ ((n >> 1) & 3)) * 16));
        }
        #pragma unroll
        for (int i = 0; i < 4; i++)
            #pragma unroll
            for (int j = 0; j < 4; j++)
                acc[i][j] = __builtin_amdgcn_mfma_f32_16x16x32_bf16(a[i], b[j], acc[i][j], 0, 0, 0);
        __syncthreads();
    }

    int colL = lane & 15, rowg = (lane >> 4) * 4;
    #pragma unroll
    for (int i = 0; i < 4; i++) {
        #pragma unroll
        for (int j = 0; j < 4; j++) {
            int col = n0 + wn + j*16 + colL;
            float bv = bias ? bias[col] : 0.0f;
            #pragma unroll
            for (int r = 0; r < 4; r++) {
                int row = m0 + wm + i*16 + rowg + r;
                float v = acc[i][j][r] + bv;
                if (flags & 4) v = fmaxf(v, 0.0f);
                size_t off = (size_t)row * ldc + col;
                if (flags & 1)      ((__hip_bfloat16*)Cp)[off] = __float2bfloat16(v);
                else if (flags & 2) ((float*)Cp)[off] += v;
                else                ((float*)Cp)[off] = v;
            }
        }
    }
}

// ---------------- attention ----------------
__global__ __launch_bounds__(256) void k_attn(const __hip_bfloat16* __restrict__ qkv,
                                              __hip_bfloat16* __restrict__ o) {
    __shared__ float qs[SEQ_][HD_], ks[SEQ_][HD_], vs[SEQ_][HD_];
    __shared__ float att[SEQ_][SEQ_];
    int blk = blockIdx.x;
    int hh  = blk % H_;
    int cbb = blk / H_;
    int t = threadIdx.x;
    for (int i = t; i < SEQ_*HD_; i += 256) {
        int s = i / HD_, d = i % HD_;
        size_t g = (size_t)(cbb*SEQ_ + s) * 2304 + hh*64 + d;
        qs[s][d] = __bfloat162float(qkv[g]);
        ks[s][d] = __bfloat162float(qkv[g + 768]);
        vs[s][d] = __bfloat162float(qkv[g + 1536]);
    }
    __syncthreads();
    if (t < SEQ_*SEQ_) {
        int qi = t / SEQ_, kj = t % SEQ_;
        float s = 0.f;
        #pragma unroll
        for (int d = 0; d < HD_; d++) s += qs[qi][d] * ks[kj][d];
        att[qi][kj] = s * 0.125f;
    }
    __syncthreads();
    if (t < SEQ_) {
        float mx = -1e30f;
        #pragma unroll
        for (int j = 0; j < SEQ_; j++) mx = fmaxf(mx, att[t][j]);
        float e[SEQ_]; float sum = 0.f;
        #pragma unroll
        for (int j = 0; j < SEQ_; j++) { e[j] = expf(att[t][j] - mx); sum += e[j]; }
        float inv = 1.f / sum;
        #pragma unroll
        for (int j = 0; j < SEQ_; j++) att[t][j] = e[j] * inv;
    }
    __syncthreads();
    for (int i = t; i < SEQ_*HD_; i += 256) {
        int s = i / HD_, d = i % HD_;
        float acc = 0.f;
        #pragma unroll
        for (int j = 0; j < SEQ_; j++) acc += att[s][j] * vs[j][d];
        o[(size_t)(cbb*SEQ_ + s) * 768 + hh*64 + d] = __float2bfloat16(acc);
    }
}

// ---------------- logits ----------------
__global__ __launch_bounds__(256) void k_logits(const __hip_bfloat16* __restrict__ hfin,
                                                const float* __restrict__ Wout,
                                                const float* __restrict__ bout,
                                                float* __restrict__ logits, int cb) {
    __shared__ float red[3][256];
    int blk = blockIdx.x;
    int t = threadIdx.x;
    const __hip_bfloat16* row = hfin + (size_t)blk * SEQ_ * E_;
    float a0 = 0.f, a1 = 0.f, a2 = 0.f;
    for (int e = t; e < SEQ_*E_; e += 256) {
        float x = __bfloat162float(row[e]);
        a0 += x * Wout[e*3 + 0]; a1 += x * Wout[e*3 + 1]; a2 += x * Wout[e*3 + 2];
    }
    red[0][t] = a0; red[1][t] = a1; red[2][t] = a2;
    __syncthreads();
    for (int o = 128; o > 0; o >>= 1) {
        if (t < o) { red[0][t] += red[0][t+o]; red[1][t] += red[1][t+o]; red[2][t] += red[2][t+o]; }
        __syncthreads();
    }
    if (t < 3) logits[((size_t)cb*B_ + blk)*3 + t] = red[t][0] + bout[t];
}

// ---------------- greedy matching: ONE wave per lidx, zero barriers in hot loop ----------------
__global__ __launch_bounds__(64) void k_match(const float* __restrict__ logits,
                                              const float* __restrict__ targets,
                                              float* __restrict__ losses) {
    __shared__ float cst[128 * 129];
    __shared__ float tg[128][3];
    __shared__ int mrow[128];
    int cl = blockIdx.x, lane = threadIdx.x;
    int lidx = cl + 1;
    for (int j = lane; j < 128; j += 64) {
        const float* t = &targets[((size_t)j*L_ + (L_ - lidx)) * 3];
        tg[j][0] = t[0]; tg[j][1] = t[1]; tg[j][2] = t[2];
    }
    __syncthreads();
    u64 rowBest[2];
    #pragma unroll
    for (int hh = 0; hh < 2; hh++) {
        int r = lane + hh*64;
        const float* lg = &logits[(cl*B_ + r) * 3];
        float l0 = lg[0], l1 = lg[1], l2 = lg[2];
        u64 best = ~0ull;
        for (int c = 0; c < 128; c++) {
            float d0 = l0 - tg[c][0], d1 = l1 - tg[c][1], d2 = l2 - tg[c][2];
            float cost = sqrtf(d0*d0 + d1*d1 + d2*d2 + 1e-12f);
            cst[r*129 + c] = cost;
            u64 key = ((u64)__float_as_uint(cost) << 32) | (unsigned)(r*128 + c);
            best = key < best ? key : best;
        }
        rowBest[hh] = best;
    }
    for (int it = 0; it < 128; it++) {
        u64 b = rowBest[0] < rowBest[1] ? rowBest[0] : rowBest[1];
        #pragma unroll
        for (int o = 32; o > 0; o >>= 1) {
            u64 other = __shfl_xor(b, o, 64);
            b = other < b ? other : b;
        }
        unsigned wi = ((unsigned)b >> 7) & 127, wj = (unsigned)b & 127;
        if (lane == 0) mrow[wi] = wj;
        #pragma unroll
        for (int hh = 0; hh < 2; hh++) {
            int r = lane + hh*64;
            if ((unsigned)r == wi) rowBest[hh] = ~0ull;
            cst[r*129 + wj] = 1e30f;
            if (rowBest[hh] != ~0ull && ((unsigned)rowBest[hh] & 127) == wj) {
                u64 best = ~0ull;
                for (int c = 0; c < 128; c++) {
                    u64 key = ((u64)__float_as_uint(cst[r*129 + c]) << 32)
                              | (unsigned)(r*128 + c);
                    best = key < best ? key : best;
                }
                rowBest[hh] = best;
            }
        }
    }
    __syncthreads();
    float a = 0.f;
    #pragma unroll
    for (int hh = 0; hh < 2; hh++) {
        int r = lane + hh*64;
        const float* lg = &logits[(cl*B_ + mrow[r]) * 3];
        float d0 = lg[0]-tg[r][0], d1 = lg[1]-tg[r][1], d2 = lg[2]-tg[r][2];
        a += d0*d0 + d1*d1 + d2*d2;
    }
    #pragma unroll
    for (int o = 32; o > 0; o >>= 1) a += __shfl_xor(a, o, 64);
    if (lane == 0) losses[cl] = a * (1.0f / (B_*3));
}

__global__ void k_final(const float* __restrict__ losses, float* __restrict__ out) {
    float s = 0.f;
    for (int i = 0; i < 15; i++) s += losses[i];
    out[0] = s * (1.0f / 15.0f);
}

extern "C" void kernel_launch(void* const* d_in, const int* in_sizes, int n_in,
                              void* d_out, int out_size, void* d_ws, size_t ws_size,
                              hipStream_t stream) {
    (void)in_sizes; (void)n_in; (void)out_size;
    const float* X       = (const float*)d_in[0];
    const float* targets = (const float*)d_in[1];
    const float* omegas  = (const float*)d_in[2];
    const float* phases  = (const float*)d_in[3];
    const int*   perms   = (const int*)d_in[4];
    const float* Wq  = (const float*)d_in[5];
    const float* bq  = (const float*)d_in[6];
    const float* Wk  = (const float*)d_in[7];
    const float* bk  = (const float*)d_in[8];
    const float* Wv  = (const float*)d_in[9];
    const float* bv  = (const float*)d_in[10];
    const float* Wo  = (const float*)d_in[11];
    const float* bo  = (const float*)d_in[12];
    const float* ln1g = (const float*)d_in[13];
    const float* ln1b = (const float*)d_in[14];
    const float* ln2g = (const float*)d_in[15];
    const float* ln2b = (const float*)d_in[16];
    const float* W1  = (const float*)d_in[17];
    const float* b1f = (const float*)d_in[18];
    const float* W2  = (const float*)d_in[19];
    const float* b2f = (const float*)d_in[20];
    const float* lnfg = (const float*)d_in[21];
    const float* lnfb = (const float*)d_in[22];
    const float* Wout = (const float*)d_in[23];
    const float* bout = (const float*)d_in[24];

    // ws_size constant across calls -> branches are call-invariant (graph-safe).
    int  CL    = (ws_size >= 306800000ull) ? 15 : 5;
    bool hoist = (CL == 15) || (ws_size >= 165300000ull);
    int  M     = CL * B_ * SEQ_;

    char* wsb = (char*)d_ws;
    size_t off = 0;
    auto alloc = [&](size_t bytes) {
        char* p = wsb + off;
        off += (bytes + 255) & ~(size_t)255;
        return p;
    };
    float*          XS     = (float*)alloc(9437184);
    float*          x      = (float*)alloc((size_t)M*E_*4);
    __hip_bfloat16* h      = (__hip_bfloat16*)alloc((size_t)M*E_*2);
    __hip_bfloat16* qkvh   = (__hip_bfloat16*)alloc((size_t)M*2304*2);
    __hip_bfloat16* wl     = (__hip_bfloat16*)alloc((hoist ? 6 : 1) * (size_t)WLS*2);
    float*          bqkv   = (float*)alloc((hoist ? 6 : 1) * (size_t)BQS*4);
    float*          logits = (float*)alloc(23040);
    float*          losses = (float*)alloc(64);

    k_xs<<<(B_*L_*3*D_ + 255)/256, 256, 0, stream>>>(X, omegas, phases, XS);

    if (hoist)
        k_cvt<<<6*6913, 256, 0, stream>>>(Wq, Wk, Wv, Wo, W1, W2, bq, bk, bv, wl, bqkv, 0);

    dim3 gQKV(2304/128, M/128);
    dim3 gO  (768/128,  M/128);
    dim3 gF1 (1536/128, M/128);
    dim3 gLN (M/4);

    for (int cb = 0; cb < 15; cb += CL) {
        k_x0<<<(M*E_)/256, 256, 0, stream>>>(XS, targets, perms, x, cb, M);
        for (int l = 0; l < NL_; l++) {
            __hip_bfloat16* wlp = hoist ? wl + (size_t)l*WLS : wl;
            float*          bqp = hoist ? bqkv + l*BQS : bqkv;
            if (!hoist)
                k_cvt<<<6913, 256, 0, stream>>>(Wq, Wk, Wv, Wo, W1, W2, bq, bk, bv, wlp, bqp, l);
            k_ln<<<gLN, 256, 0, stream>>>(x, ln1g + l*E_, ln1b + l*E_, h);
            k_gemm<<<gQKV, 256, 0, stream>>>(h, wlp, bqp, qkvh, 768, 768, 2304, 1);
            k_attn<<<CL*B_*H_, 256, 0, stream>>>(qkvh, h);
            k_gemm<<<gO, 256, 0, stream>>>(h, wlp + 1769472, bo + l*E_, x, 768, 768, 768, 2);
            k_ln<<<gLN, 256, 0, stream>>>(x, ln2g + l*E_, ln2b + l*E_, h);
            for (int nc = 0; nc < 2; nc++) {
                // hidden = relu(h @ W1t_chunk^T): W1t rows contiguous len 768 (ldb=768)
                k_gemm<<<gF1, 256, 0, stream>>>(h, wlp + 2359296 + (size_t)nc*1536*768,
                                                b1f + l*3072 + nc*1536, qkvh, 768, 768, 1536, 1|4);
                // x += hidden @ W2t_chunk^T: W2t row stride 3072, chunk col offset nc*1536 (ldb=3072)
                k_gemm<<<gO, 256, 0, stream>>>(qkvh, wlp + 4718592 + (size_t)nc*1536,
                                               nc == 0 ? (b2f + l*E_) : (const float*)nullptr,
                                               x, 1536, 3072, 768, 2);
            }
        }
        k_ln<<<gLN, 256, 0, stream>>>(x, lnfg, lnfb, h);
        k_logits<<<CL*B_, 256, 0, stream>>>(h, Wout, bout, logits, cb);
    }
    k_match<<<15, 64, 0, stream>>>(logits, targets, losses);
    k_final<<<1, 1, 0, stream>>>(losses, (float*)d_out);
}

// Round 6
// 5696.412 us; speedup vs baseline: 1.2152x; 1.2152x over previous
//
#include <hip/hip_runtime.h>
#include <hip/hip_bf16.h>
#include <math.h>

#define B_   128
#define L_   16
#define E_   768
#define D_   384
#define H_   12
#define HD_  64
#define NL_  6
#define SEQ_ 12
#define LN_EPS 0.001f
#define WLS   7077888               // bf16 elems per layer weight pack
#define BQS   2304

typedef __attribute__((ext_vector_type(8))) short bf16x8;
typedef __attribute__((ext_vector_type(4))) float f32x4;
typedef unsigned long long u64;

#define GLOAD_LDS16(g, l) \
    __builtin_amdgcn_global_load_lds((__attribute__((address_space(1))) const void*)(g), \
                                     (__attribute__((address_space(3))) void*)(l), 16, 0, 0)

// ---------------- XS = cos(X*omega + phase) ----------------
__global__ __launch_bounds__(256) void k_xs(const float* __restrict__ X,
                                            const float* __restrict__ om,
                                            const float* __restrict__ ph,
                                            float* __restrict__ XS) {
    int i = blockIdx.x * 256 + threadIdx.x;
    if (i >= B_*L_*3*D_) return;
    int d  = i % D_;
    int ch = (i / D_) % 3;
    int bt = i / (3*D_);
    XS[i] = cosf(X[bt*3 + ch] * om[ch*D_ + d] + ph[ch*D_ + d]);
}

// ---------------- build x0 for CL lidx starting at cb ----------------
__global__ __launch_bounds__(256) void k_x0(const float* __restrict__ XS,
                                            const float* __restrict__ targets,
                                            const int* __restrict__ perms,
                                            float* __restrict__ x, int cb, int ntok) {
    int i = blockIdx.x * 256 + threadIdx.x;
    if (i >= ntok*E_) return;
    int e   = i % E_;
    int tok = i / E_;
    int s   = tok % SEQ_;
    int bi  = (tok / SEQ_) % B_;
    int c   = tok / (SEQ_*B_);
    int cl  = cb + c;
    int lidx = cl + 1;
    int pb  = perms[cl*B_ + bi];
    float val;
    if (s < 3) {
        int t = (e < D_) ? (L_ - lidx) : (L_ - lidx - 1);
        int d = (e < D_) ? e : (e - D_);
        val = XS[((pb*L_ + t)*3 + s)*D_ + d];
    } else if (s < 6) {
        int t = (17 - lidx) & 15;
        val = targets[(pb*L_ + t)*3 + (s - 3)];
    } else {
        val = (float)(L_ - lidx);
    }
    x[i] = val;
}

// ---------------- LayerNorm: one wave per token, no barriers ----------------
__global__ __launch_bounds__(256) void k_ln(const float* __restrict__ x,
                                            const float* __restrict__ g,
                                            const float* __restrict__ b,
                                            __hip_bfloat16* __restrict__ h) {
    int gi = blockIdx.x * 256 + threadIdx.x;
    int tok = gi >> 6, lane = gi & 63;
    const float4* xr = (const float4*)(x + (size_t)tok * E_);
    float4 v0 = xr[lane], v1 = xr[lane + 64], v2 = xr[lane + 128];
    float s = v0.x+v0.y+v0.z+v0.w + v1.x+v1.y+v1.z+v1.w + v2.x+v2.y+v2.z+v2.w;
    #pragma unroll
    for (int o = 32; o > 0; o >>= 1) s += __shfl_xor(s, o, 64);
    float mu = s * (1.0f / E_);
    v0.x-=mu; v0.y-=mu; v0.z-=mu; v0.w-=mu;
    v1.x-=mu; v1.y-=mu; v1.z-=mu; v1.w-=mu;
    v2.x-=mu; v2.y-=mu; v2.z-=mu; v2.w-=mu;
    float q = v0.x*v0.x+v0.y*v0.y+v0.z*v0.z+v0.w*v0.w
            + v1.x*v1.x+v1.y*v1.y+v1.z*v1.z+v1.w*v1.w
            + v2.x*v2.x+v2.y*v2.y+v2.z*v2.z+v2.w*v2.w;
    #pragma unroll
    for (int o = 32; o > 0; o >>= 1) q += __shfl_xor(q, o, 64);
    float rstd = rsqrtf(q * (1.0f / E_) + LN_EPS);
    const float4* g4 = (const float4*)g;
    const float4* b4 = (const float4*)b;
    ushort4* h4 = (ushort4*)(h + (size_t)tok * E_);
    #pragma unroll
    for (int k = 0; k < 3; k++) {
        float4 v = (k == 0) ? v0 : (k == 1) ? v1 : v2;
        float4 gg = g4[lane + k*64], bb = b4[lane + k*64];
        ushort4 o;
        o.x = __bfloat16_as_ushort(__float2bfloat16(v.x * rstd * gg.x + bb.x));
        o.y = __bfloat16_as_ushort(__float2bfloat16(v.y * rstd * gg.y + bb.y));
        o.z = __bfloat16_as_ushort(__float2bfloat16(v.z * rstd * gg.z + bb.z));
        o.w = __bfloat16_as_ushort(__float2bfloat16(v.w * rstd * gg.w + bb.w));
        h4[lane + k*64] = o;
    }
}

// ---------------- weight transpose+convert fp32[K][N] -> bf16[N][K], nl layers ----------------
__global__ __launch_bounds__(256) void k_cvt(const float* __restrict__ Wq,
                                             const float* __restrict__ Wk,
                                             const float* __restrict__ Wv,
                                             const float* __restrict__ Wo,
                                             const float* __restrict__ W1,
                                             const float* __restrict__ W2,
                                             const float* __restrict__ bq,
                                             const float* __restrict__ bk,
                                             const float* __restrict__ bv,
                                             __hip_bfloat16* __restrict__ wl0,
                                             float* __restrict__ bqkv0, int lbase) {
    int bid = blockIdx.x;
    int l   = lbase + bid / 6913;
    bid %= 6913;
    __hip_bfloat16* wl = wl0 + (size_t)(l - lbase) * WLS;
    float* bqkv = bqkv0 + (l - lbase) * BQS;
    int tid = threadIdx.x;
    if (bid == 6912) {
        for (int i = tid; i < 2304; i += 256) {
            float v = (i < 768) ? bq[l*768 + i] : (i < 1536) ? bk[l*768 + i - 768]
                                                             : bv[l*768 + i - 1536];
            bqkv[i] = v;
        }
        return;
    }
    const float* src; __hip_bfloat16* dst; int K, N, ti, tj;
    if (bid < 1728) {
        int part = bid / 576, idx = bid % 576;
        const float* srcs[3] = {Wq, Wk, Wv};
        src = srcs[part] + (size_t)l*768*768; dst = wl + (size_t)part*768*768;
        K = 768; N = 768; tj = idx % 24; ti = idx / 24;
    } else if (bid < 2304) {
        int idx = bid - 1728;
        src = Wo + (size_t)l*768*768; dst = wl + 1769472;
        K = 768; N = 768; tj = idx % 24; ti = idx / 24;
    } else if (bid < 4608) {
        int idx = bid - 2304;
        src = W1 + (size_t)l*768*3072; dst = wl + 2359296;
        K = 768; N = 3072; tj = idx % 96; ti = idx / 96;
    } else {
        int idx = bid - 4608;
        src = W2 + (size_t)l*3072*768; dst = wl + 4718592;
        K = 3072; N = 768; tj = idx % 24; ti = idx / 24;
    }
    __shared__ float tbuf[32][33];
    int tx = tid & 31, ty = tid >> 5;
    #pragma unroll
    for (int p = 0; p < 4; p++) {
        int k = ti*32 + ty + p*8, n = tj*32 + tx;
        tbuf[ty + p*8][tx] = src[(size_t)k*N + n];
    }
    __syncthreads();
    #pragma unroll
    for (int p = 0; p < 4; p++) {
        int n = tj*32 + ty + p*8, k = ti*32 + tx;
        dst[(size_t)n*K + k] = __float2bfloat16(tbuf[tx][ty + p*8]);
    }
}

// ---------------- bf16 MFMA GEMM: C(+)= A[M][K] @ Bt[N][K]^T, tile 128xBN_ ----------------
// A row stride == K; Bt row stride == ldb. flags: 1=bf16 out, 2=fp32 +=, 4=relu
template<int BN_>
__global__ __launch_bounds__(256) void k_gemm_t(const __hip_bfloat16* __restrict__ A,
                                                const __hip_bfloat16* __restrict__ Bt,
                                                const float* __restrict__ bias,
                                                void* __restrict__ Cp,
                                                int K, int ldb, int ldc, int flags) {
    constexpr int NF = BN_ / 32;                  // B frags per wave (4 or 2)
    __shared__ __align__(16) char smem[8192 + BN_*64];
    char* As = smem;
    char* Bs = smem + 8192;
    int tid = threadIdx.x;
    int lane = tid & 63;
    int w = tid >> 6;
    int wm = (w >> 1) * 64, wn = (w & 1) * (BN_/2);
    int m0 = blockIdx.y * 128, n0 = blockIdx.x * BN_;

    int u1 = tid, u2 = tid + 256;
    int r1 = u1 >> 2, kg1 = ((u1 & 3) ^ ((r1 >> 1) & 3)) * 8;
    int r2 = u2 >> 2, kg2 = ((u2 & 3) ^ ((r2 >> 1) & 3)) * 8;

    f32x4 acc[4][NF] = {};
    int fr = lane & 15, fkg = lane >> 4;

    for (int k0 = 0; k0 < K; k0 += 32) {
        GLOAD_LDS16(A  + (size_t)(m0 + r1) * K   + k0 + kg1, As + u1 * 16);
        GLOAD_LDS16(A  + (size_t)(m0 + r2) * K   + k0 + kg2, As + u2 * 16);
        GLOAD_LDS16(Bt + (size_t)(n0 + r1) * ldb + k0 + kg1, Bs + u1 * 16);
        if (BN_ == 128)
            GLOAD_LDS16(Bt + (size_t)(n0 + r2) * ldb + k0 + kg2, Bs + u2 * 16);
        __syncthreads();
        bf16x8 a[4], b[NF];
        #pragma unroll
        for (int i = 0; i < 4; i++) {
            int m = wm + i*16 + fr;
            a[i] = *(const bf16x8*)(As + m*64 + ((fkg ^ ((m >> 1) & 3)) * 16));
        }
        #pragma unroll
        for (int j = 0; j < NF; j++) {
            int n = wn + j*16 + fr;
            b[j] = *(const bf16x8*)(Bs + n*64 + ((fkg ^ ((n >> 1) & 3)) * 16));
        }
        #pragma unroll
        for (int i = 0; i < 4; i++)
            #pragma unroll
            for (int j = 0; j < NF; j++)
                acc[i][j] = __builtin_amdgcn_mfma_f32_16x16x32_bf16(a[i], b[j], acc[i][j], 0, 0, 0);
        __syncthreads();
    }

    int colL = lane & 15, rowg = (lane >> 4) * 4;
    #pragma unroll
    for (int i = 0; i < 4; i++) {
        #pragma unroll
        for (int j = 0; j < NF; j++) {
            int col = n0 + wn + j*16 + colL;
            float bv = bias ? bias[col] : 0.0f;
            #pragma unroll
            for (int r = 0; r < 4; r++) {
                int row = m0 + wm + i*16 + rowg + r;
                float v = acc[i][j][r] + bv;
                if (flags & 4) v = fmaxf(v, 0.0f);
                size_t off = (size_t)row * ldc + col;
                if (flags & 1)      ((__hip_bfloat16*)Cp)[off] = __float2bfloat16(v);
                else if (flags & 2) ((float*)Cp)[off] += v;
                else                ((float*)Cp)[off] = v;
            }
        }
    }
}

// ---------------- attention ----------------
__global__ __launch_bounds__(256) void k_attn(const __hip_bfloat16* __restrict__ qkv,
                                              __hip_bfloat16* __restrict__ o) {
    __shared__ float qs[SEQ_][HD_], ks[SEQ_][HD_], vs[SEQ_][HD_];
    __shared__ float att[SEQ_][SEQ_];
    int blk = blockIdx.x;
    int hh  = blk % H_;
    int cbb = blk / H_;
    int t = threadIdx.x;
    for (int i = t; i < SEQ_*HD_; i += 256) {
        int s = i / HD_, d = i % HD_;
        size_t g = (size_t)(cbb*SEQ_ + s) * 2304 + hh*64 + d;
        qs[s][d] = __bfloat162float(qkv[g]);
        ks[s][d] = __bfloat162float(qkv[g + 768]);
        vs[s][d] = __bfloat162float(qkv[g + 1536]);
    }
    __syncthreads();
    if (t < SEQ_*SEQ_) {
        int qi = t / SEQ_, kj = t % SEQ_;
        float s = 0.f;
        #pragma unroll
        for (int d = 0; d < HD_; d++) s += qs[qi][d] * ks[kj][d];
        att[qi][kj] = s * 0.125f;
    }
    __syncthreads();
    if (t < SEQ_) {
        float mx = -1e30f;
        #pragma unroll
        for (int j = 0; j < SEQ_; j++) mx = fmaxf(mx, att[t][j]);
        float e[SEQ_]; float sum = 0.f;
        #pragma unroll
        for (int j = 0; j < SEQ_; j++) { e[j] = expf(att[t][j] - mx); sum += e[j]; }
        float inv = 1.f / sum;
        #pragma unroll
        for (int j = 0; j < SEQ_; j++) att[t][j] = e[j] * inv;
    }
    __syncthreads();
    for (int i = t; i < SEQ_*HD_; i += 256) {
        int s = i / HD_, d = i % HD_;
        float acc = 0.f;
        #pragma unroll
        for (int j = 0; j < SEQ_; j++) acc += att[s][j] * vs[j][d];
        o[(size_t)(cbb*SEQ_ + s) * 768 + hh*64 + d] = __float2bfloat16(acc);
    }
}

// ---------------- logits ----------------
__global__ __launch_bounds__(256) void k_logits(const __hip_bfloat16* __restrict__ hfin,
                                                const float* __restrict__ Wout,
                                                const float* __restrict__ bout,
                                                float* __restrict__ logits, int cb) {
    __shared__ float red[3][256];
    int blk = blockIdx.x;
    int t = threadIdx.x;
    const __hip_bfloat16* row = hfin + (size_t)blk * SEQ_ * E_;
    float a0 = 0.f, a1 = 0.f, a2 = 0.f;
    for (int e = t; e < SEQ_*E_; e += 256) {
        float x = __bfloat162float(row[e]);
        a0 += x * Wout[e*3 + 0]; a1 += x * Wout[e*3 + 1]; a2 += x * Wout[e*3 + 2];
    }
    red[0][t] = a0; red[1][t] = a1; red[2][t] = a2;
    __syncthreads();
    for (int o = 128; o > 0; o >>= 1) {
        if (t < o) { red[0][t] += red[0][t+o]; red[1][t] += red[1][t+o]; red[2][t] += red[2][t+o]; }
        __syncthreads();
    }
    if (t < 3) logits[((size_t)cb*B_ + blk)*3 + t] = red[t][0] + bout[t];
}

// ---------------- greedy matching: 128 threads, 1 row/lane, costs in VGPRs ----------------
// Rescan is a register-only unrolled loop (no LDS latency). Key = (costbits<<14)|(r<<7|c)
// reproduces the reference's stable-argsort tie-break exactly.
__global__ __launch_bounds__(128) void k_match(const float* __restrict__ logits,
                                               const float* __restrict__ targets,
                                               float* __restrict__ losses) {
    __shared__ float tg[128][3];
    __shared__ u64 wbest[2];
    __shared__ int mrow[128];
    __shared__ float lsum[2];
    int cl = blockIdx.x, t = threadIdx.x;          // t = my row
    int lidx = cl + 1;
    int lane = t & 63, w = t >> 6;
    const float* tp = &targets[((size_t)t*L_ + (L_ - lidx)) * 3];
    tg[t][0] = tp[0]; tg[t][1] = tp[1]; tg[t][2] = tp[2];
    __syncthreads();
    const float* lg = &logits[(cl*B_ + t) * 3];
    float l0 = lg[0], l1 = lg[1], l2 = lg[2];
    float cst[128];
    u64 rbest = ~0ull;
    #pragma unroll
    for (int c = 0; c < 128; c++) {
        float d0 = l0 - tg[c][0], d1 = l1 - tg[c][1], d2 = l2 - tg[c][2];
        float cc = sqrtf(d0*d0 + d1*d1 + d2*d2 + 1e-12f);
        cst[c] = cc;
        u64 key = ((u64)__float_as_uint(cc) << 14) | (unsigned)(t*128 + c);
        rbest = key < rbest ? key : rbest;
    }
    u64 dead0 = 0, dead1 = 0;
    for (int it = 0; it < 128; it++) {
        u64 b = rbest;
        #pragma unroll
        for (int o = 32; o > 0; o >>= 1) {
            u64 x = __shfl_xor(b, o, 64);
            b = x < b ? x : b;
        }
        if (lane == 0) wbest[w] = b;
        __syncthreads();
        u64 g = wbest[0] < wbest[1] ? wbest[0] : wbest[1];
        unsigned e  = (unsigned)(g & 0x3fff);
        unsigned wi = e >> 7, wj = e & 127;
        if (t == (int)wi) { mrow[wi] = wj; rbest = ~0ull; }
        if (wj < 64) dead0 |= 1ull << wj; else dead1 |= 1ull << (wj - 64);
        if (rbest != ~0ull && ((unsigned)rbest & 127) == wj) {
            u64 nb = ~0ull;
            #pragma unroll
            for (int c = 0; c < 128; c++) {
                bool d = (((c < 64) ? dead0 : dead1) >> (c & 63)) & 1;
                u64 key = ((u64)__float_as_uint(cst[c]) << 14) | (unsigned)(t*128 + c);
                key = d ? ~0ull : key;
                nb = key < nb ? key : nb;
            }
            rbest = nb;
        }
        __syncthreads();                           // protect wbest before next write
    }
    const float* lgm = &logits[(cl*B_ + mrow[t]) * 3];
    float d0 = lgm[0]-tg[t][0], d1 = lgm[1]-tg[t][1], d2 = lgm[2]-tg[t][2];
    float a = d0*d0 + d1*d1 + d2*d2;
    #pragma unroll
    for (int o = 32; o > 0; o >>= 1) a += __shfl_xor(a, o, 64);
    if (lane == 0) lsum[w] = a;
    __syncthreads();
    if (t == 0) losses[cl] = (lsum[0] + lsum[1]) * (1.0f / (B_*3));
}

__global__ void k_final(const float* __restrict__ losses, float* __restrict__ out) {
    float s = 0.f;
    for (int i = 0; i < 15; i++) s += losses[i];
    out[0] = s * (1.0f / 15.0f);
}

extern "C" void kernel_launch(void* const* d_in, const int* in_sizes, int n_in,
                              void* d_out, int out_size, void* d_ws, size_t ws_size,
                              hipStream_t stream) {
    (void)in_sizes; (void)n_in; (void)out_size;
    const float* X       = (const float*)d_in[0];
    const float* targets = (const float*)d_in[1];
    const float* omegas  = (const float*)d_in[2];
    const float* phases  = (const float*)d_in[3];
    const int*   perms   = (const int*)d_in[4];
    const float* Wq  = (const float*)d_in[5];
    const float* bq  = (const float*)d_in[6];
    const float* Wk  = (const float*)d_in[7];
    const float* bk  = (const float*)d_in[8];
    const float* Wv  = (const float*)d_in[9];
    const float* bv  = (const float*)d_in[10];
    const float* Wo  = (const float*)d_in[11];
    const float* bo  = (const float*)d_in[12];
    const float* ln1g = (const float*)d_in[13];
    const float* ln1b = (const float*)d_in[14];
    const float* ln2g = (const float*)d_in[15];
    const float* ln2b = (const float*)d_in[16];
    const float* W1  = (const float*)d_in[17];
    const float* b1f = (const float*)d_in[18];
    const float* W2  = (const float*)d_in[19];
    const float* b2f = (const float*)d_in[20];
    const float* lnfg = (const float*)d_in[21];
    const float* lnfb = (const float*)d_in[22];
    const float* Wout = (const float*)d_in[23];
    const float* bout = (const float*)d_in[24];

    // ws_size constant across calls -> branches are call-invariant (graph-safe).
    // FULL : all 15 lidx, M=23040, weights hoisted            (~342.3 MB)
    // MID  : 3 chunks of 5, M=7680, weights hoisted           (~177.1 MB)
    // SMALL: 3 chunks of 5, per-layer weight convert          (~106.3 MB)
    int  CL    = (ws_size >= 343000000ull) ? 15 : 5;
    bool hoist = (CL == 15) || (ws_size >= 178000000ull);
    int  M     = CL * B_ * SEQ_;

    char* wsb = (char*)d_ws;
    size_t off = 0;
    auto alloc = [&](size_t bytes) {
        char* p = wsb + off;
        off += (bytes + 255) & ~(size_t)255;
        return p;
    };
    float*          XS     = (float*)alloc(9437184);
    float*          x      = (float*)alloc((size_t)M*E_*4);
    __hip_bfloat16* h      = (__hip_bfloat16*)alloc((size_t)M*E_*2);
    __hip_bfloat16* qkvh   = (__hip_bfloat16*)alloc((size_t)M*3072*2);  // qkv(2304) | ffn hidden(3072)
    __hip_bfloat16* wl     = (__hip_bfloat16*)alloc((hoist ? 6 : 1) * (size_t)WLS*2);
    float*          bqkv   = (float*)alloc((hoist ? 6 : 1) * (size_t)BQS*4);
    float*          logits = (float*)alloc(23040);
    float*          losses = (float*)alloc(64);

    k_xs<<<(B_*L_*3*D_ + 255)/256, 256, 0, stream>>>(X, omegas, phases, XS);

    if (hoist)
        k_cvt<<<6*6913, 256, 0, stream>>>(Wq, Wk, Wv, Wo, W1, W2, bq, bk, bv, wl, bqkv, 0);

    dim3 gQKV(2304/128, M/128);
    dim3 gF1 (3072/128, M/128);
    dim3 gN64(768/64,   M/128);
    dim3 gLN (M/4);

    for (int cb = 0; cb < 15; cb += CL) {
        k_x0<<<(M*E_)/256, 256, 0, stream>>>(XS, targets, perms, x, cb, M);
        for (int l = 0; l < NL_; l++) {
            __hip_bfloat16* wlp = hoist ? wl + (size_t)l*WLS : wl;
            float*          bqp = hoist ? bqkv + l*BQS : bqkv;
            if (!hoist)
                k_cvt<<<6913, 256, 0, stream>>>(Wq, Wk, Wv, Wo, W1, W2, bq, bk, bv, wlp, bqp, l);
            k_ln<<<gLN, 256, 0, stream>>>(x, ln1g + l*E_, ln1b + l*E_, h);
            k_gemm_t<128><<<gQKV, 256, 0, stream>>>(h, wlp, bqp, qkvh, 768, 768, 2304, 1);
            k_attn<<<CL*B_*H_, 256, 0, stream>>>(qkvh, h);
            k_gemm_t<64><<<gN64, 256, 0, stream>>>(h, wlp + 1769472, bo + l*E_, x,
                                                   768, 768, 768, 2);
            k_ln<<<gLN, 256, 0, stream>>>(x, ln2g + l*E_, ln2b + l*E_, h);
            // hidden = relu(h @ W1t^T): W1t [3072][768], ldb=768; out ldc=3072 into qkvh
            k_gemm_t<128><<<gF1, 256, 0, stream>>>(h, wlp + 2359296, b1f + l*3072, qkvh,
                                                   768, 768, 3072, 1|4);
            // x += hidden @ W2t^T: W2t [768][3072], ldb=3072
            k_gemm_t<64><<<gN64, 256, 0, stream>>>(qkvh, wlp + 4718592, b2f + l*E_, x,
                                                   3072, 3072, 768, 2);
        }
        k_ln<<<gLN, 256, 0, stream>>>(x, lnfg, lnfb, h);
        k_logits<<<CL*B_, 256, 0, stream>>>(h, Wout, bout, logits, cb);
    }
    k_match<<<15, 128, 0, stream>>>(logits, targets, losses);
    k_final<<<1, 1, 0, stream>>>(losses, (float*)d_out);
}

// Round 7
// 5088.817 us; speedup vs baseline: 1.3603x; 1.1194x over previous
//
#include <hip/hip_runtime.h>
#include <hip/hip_bf16.h>
#include <math.h>

#define B_   128
#define L_   16
#define E_   768
#define D_   384
#define H_   12
#define HD_  64
#define NL_  6
#define SEQ_ 12
#define LN_EPS 0.001f
#define WLS   7077888               // bf16 elems per layer weight pack
#define BQS   2304

typedef __attribute__((ext_vector_type(8))) short bf16x8;
typedef __attribute__((ext_vector_type(4))) float f32x4;
typedef unsigned long long u64;

#define GLOAD_LDS16(g, l) \
    __builtin_amdgcn_global_load_lds((__attribute__((address_space(1))) const void*)(g), \
                                     (__attribute__((address_space(3))) void*)(l), 16, 0, 0)

// ---------------- build x0 for CL lidx starting at cb (cos inlined) ----------------
__global__ __launch_bounds__(256) void k_x0(const float* __restrict__ X,
                                            const float* __restrict__ targets,
                                            const int* __restrict__ perms,
                                            const float* __restrict__ om,
                                            const float* __restrict__ ph,
                                            float* __restrict__ x, int cb, int ntok) {
    int i = blockIdx.x * 256 + threadIdx.x;
    if (i >= ntok*E_) return;
    int e   = i % E_;
    int tok = i / E_;
    int s   = tok % SEQ_;
    int bi  = (tok / SEQ_) % B_;
    int c   = tok / (SEQ_*B_);
    int cl  = cb + c;
    int lidx = cl + 1;
    int pb  = perms[cl*B_ + bi];
    float val;
    if (s < 3) {
        int t  = (e < D_) ? (L_ - lidx) : (L_ - lidx - 1);
        int dd = (e < D_) ? e : (e - D_);
        float xv = X[(pb*L_ + t)*3 + s];
        val = cosf(xv * om[s*D_ + dd] + ph[s*D_ + dd]);
    } else if (s < 6) {
        int t = (17 - lidx) & 15;
        val = targets[(pb*L_ + t)*3 + (s - 3)];
    } else {
        val = (float)(L_ - lidx);
    }
    x[i] = val;
}

// ---------------- LayerNorm: one wave per token, no barriers ----------------
__global__ __launch_bounds__(256) void k_ln(const float* __restrict__ x,
                                            const float* __restrict__ g,
                                            const float* __restrict__ b,
                                            __hip_bfloat16* __restrict__ h) {
    int gi = blockIdx.x * 256 + threadIdx.x;
    int tok = gi >> 6, lane = gi & 63;
    const float4* xr = (const float4*)(x + (size_t)tok * E_);
    float4 v0 = xr[lane], v1 = xr[lane + 64], v2 = xr[lane + 128];
    float s = v0.x+v0.y+v0.z+v0.w + v1.x+v1.y+v1.z+v1.w + v2.x+v2.y+v2.z+v2.w;
    #pragma unroll
    for (int o = 32; o > 0; o >>= 1) s += __shfl_xor(s, o, 64);
    float mu = s * (1.0f / E_);
    v0.x-=mu; v0.y-=mu; v0.z-=mu; v0.w-=mu;
    v1.x-=mu; v1.y-=mu; v1.z-=mu; v1.w-=mu;
    v2.x-=mu; v2.y-=mu; v2.z-=mu; v2.w-=mu;
    float q = v0.x*v0.x+v0.y*v0.y+v0.z*v0.z+v0.w*v0.w
            + v1.x*v1.x+v1.y*v1.y+v1.z*v1.z+v1.w*v1.w
            + v2.x*v2.x+v2.y*v2.y+v2.z*v2.z+v2.w*v2.w;
    #pragma unroll
    for (int o = 32; o > 0; o >>= 1) q += __shfl_xor(q, o, 64);
    float rstd = rsqrtf(q * (1.0f / E_) + LN_EPS);
    const float4* g4 = (const float4*)g;
    const float4* b4 = (const float4*)b;
    ushort4* h4 = (ushort4*)(h + (size_t)tok * E_);
    #pragma unroll
    for (int k = 0; k < 3; k++) {
        float4 v = (k == 0) ? v0 : (k == 1) ? v1 : v2;
        float4 gg = g4[lane + k*64], bb = b4[lane + k*64];
        ushort4 o;
        o.x = __bfloat16_as_ushort(__float2bfloat16(v.x * rstd * gg.x + bb.x));
        o.y = __bfloat16_as_ushort(__float2bfloat16(v.y * rstd * gg.y + bb.y));
        o.z = __bfloat16_as_ushort(__float2bfloat16(v.z * rstd * gg.z + bb.z));
        o.w = __bfloat16_as_ushort(__float2bfloat16(v.w * rstd * gg.w + bb.w));
        h4[lane + k*64] = o;
    }
}

// ---------------- weight transpose+convert fp32[K][N] -> bf16[N][K], nl layers ----------------
__global__ __launch_bounds__(256) void k_cvt(const float* __restrict__ Wq,
                                             const float* __restrict__ Wk,
                                             const float* __restrict__ Wv,
                                             const float* __restrict__ Wo,
                                             const float* __restrict__ W1,
                                             const float* __restrict__ W2,
                                             const float* __restrict__ bq,
                                             const float* __restrict__ bk,
                                             const float* __restrict__ bv,
                                             __hip_bfloat16* __restrict__ wl0,
                                             float* __restrict__ bqkv0, int lbase) {
    int bid = blockIdx.x;
    int l   = lbase + bid / 6913;
    bid %= 6913;
    __hip_bfloat16* wl = wl0 + (size_t)(l - lbase) * WLS;
    float* bqkv = bqkv0 + (l - lbase) * BQS;
    int tid = threadIdx.x;
    if (bid == 6912) {
        for (int i = tid; i < 2304; i += 256) {
            float v = (i < 768) ? bq[l*768 + i] : (i < 1536) ? bk[l*768 + i - 768]
                                                             : bv[l*768 + i - 1536];
            bqkv[i] = v;
        }
        return;
    }
    const float* src; __hip_bfloat16* dst; int K, N, ti, tj;
    if (bid < 1728) {
        int part = bid / 576, idx = bid % 576;
        const float* srcs[3] = {Wq, Wk, Wv};
        src = srcs[part] + (size_t)l*768*768; dst = wl + (size_t)part*768*768;
        K = 768; N = 768; tj = idx % 24; ti = idx / 24;
    } else if (bid < 2304) {
        int idx = bid - 1728;
        src = Wo + (size_t)l*768*768; dst = wl + 1769472;
        K = 768; N = 768; tj = idx % 24; ti = idx / 24;
    } else if (bid < 4608) {
        int idx = bid - 2304;
        src = W1 + (size_t)l*768*3072; dst = wl + 2359296;
        K = 768; N = 3072; tj = idx % 96; ti = idx / 96;
    } else {
        int idx = bid - 4608;
        src = W2 + (size_t)l*3072*768; dst = wl + 4718592;
        K = 3072; N = 768; tj = idx % 24; ti = idx / 24;
    }
    __shared__ float tbuf[32][33];
    int tx = tid & 31, ty = tid >> 5;
    #pragma unroll
    for (int p = 0; p < 4; p++) {
        int k = ti*32 + ty + p*8, n = tj*32 + tx;
        tbuf[ty + p*8][tx] = src[(size_t)k*N + n];
    }
    __syncthreads();
    #pragma unroll
    for (int p = 0; p < 4; p++) {
        int n = tj*32 + ty + p*8, k = ti*32 + tx;
        dst[(size_t)n*K + k] = __float2bfloat16(tbuf[tx][ty + p*8]);
    }
}

// ---------------- bf16 MFMA GEMM: C(+)= A[M][K] @ Bt[N][K]^T, tile 128xBN_ ----------------
// A row stride == K; Bt row stride == ldb. flags: 1=bf16 out, 2=fp32 +=, 4=relu
template<int BN_>
__global__ __launch_bounds__(256) void k_gemm_t(const __hip_bfloat16* __restrict__ A,
                                                const __hip_bfloat16* __restrict__ Bt,
                                                const float* __restrict__ bias,
                                                void* __restrict__ Cp,
                                                int K, int ldb, int ldc, int flags) {
    constexpr int NF = BN_ / 32;
    __shared__ __align__(16) char smem[8192 + BN_*64];
    char* As = smem;
    char* Bs = smem + 8192;
    int tid = threadIdx.x;
    int lane = tid & 63;
    int w = tid >> 6;
    int wm = (w >> 1) * 64, wn = (w & 1) * (BN_/2);
    int m0 = blockIdx.y * 128, n0 = blockIdx.x * BN_;

    int u1 = tid, u2 = tid + 256;
    int r1 = u1 >> 2, kg1 = ((u1 & 3) ^ ((r1 >> 1) & 3)) * 8;
    int r2 = u2 >> 2, kg2 = ((u2 & 3) ^ ((r2 >> 1) & 3)) * 8;

    f32x4 acc[4][NF] = {};
    int fr = lane & 15, fkg = lane >> 4;

    for (int k0 = 0; k0 < K; k0 += 32) {
        GLOAD_LDS16(A  + (size_t)(m0 + r1) * K   + k0 + kg1, As + u1 * 16);
        GLOAD_LDS16(A  + (size_t)(m0 + r2) * K   + k0 + kg2, As + u2 * 16);
        GLOAD_LDS16(Bt + (size_t)(n0 + r1) * ldb + k0 + kg1, Bs + u1 * 16);
        if (BN_ == 128)
            GLOAD_LDS16(Bt + (size_t)(n0 + r2) * ldb + k0 + kg2, Bs + u2 * 16);
        __syncthreads();
        bf16x8 a[4], b[NF];
        #pragma unroll
        for (int i = 0; i < 4; i++) {
            int m = wm + i*16 + fr;
            a[i] = *(const bf16x8*)(As + m*64 + ((fkg ^ ((m >> 1) & 3)) * 16));
        }
        #pragma unroll
        for (int j = 0; j < NF; j++) {
            int n = wn + j*16 + fr;
            b[j] = *(const bf16x8*)(Bs + n*64 + ((fkg ^ ((n >> 1) & 3)) * 16));
        }
        #pragma unroll
        for (int i = 0; i < 4; i++)
            #pragma unroll
            for (int j = 0; j < NF; j++)
                acc[i][j] = __builtin_amdgcn_mfma_f32_16x16x32_bf16(a[i], b[j], acc[i][j], 0, 0, 0);
        __syncthreads();
    }

    int colL = lane & 15, rowg = (lane >> 4) * 4;
    #pragma unroll
    for (int i = 0; i < 4; i++) {
        #pragma unroll
        for (int j = 0; j < NF; j++) {
            int col = n0 + wn + j*16 + colL;
            float bv = bias ? bias[col] : 0.0f;
            #pragma unroll
            for (int r = 0; r < 4; r++) {
                int row = m0 + wm + i*16 + rowg + r;
                float v = acc[i][j][r] + bv;
                if (flags & 4) v = fmaxf(v, 0.0f);
                size_t off = (size_t)row * ldc + col;
                if (flags & 1)      ((__hip_bfloat16*)Cp)[off] = __float2bfloat16(v);
                else if (flags & 2) ((float*)Cp)[off] += v;
                else                ((float*)Cp)[off] = v;
            }
        }
    }
}

// ---------------- attention (vectorized bf16x8 loads) ----------------
__global__ __launch_bounds__(256) void k_attn(const __hip_bfloat16* __restrict__ qkv,
                                              __hip_bfloat16* __restrict__ o) {
    __shared__ float qs[SEQ_][HD_], ks[SEQ_][HD_], vs[SEQ_][HD_];
    __shared__ float att[SEQ_][SEQ_];
    int blk = blockIdx.x;
    int hh  = blk % H_;
    int cbb = blk / H_;
    int t = threadIdx.x;
    if (t < 96) {                          // 12 rows x 8 chunks of 8 elems
        int s = t >> 3, c = (t & 7) * 8;
        size_t base = (size_t)(cbb*SEQ_ + s) * 2304 + hh*64 + c;
        bf16x8 q8 = *(const bf16x8*)(qkv + base);
        bf16x8 k8 = *(const bf16x8*)(qkv + base + 768);
        bf16x8 v8 = *(const bf16x8*)(qkv + base + 1536);
        #pragma unroll
        for (int j = 0; j < 8; j++) {
            qs[s][c+j] = __uint_as_float((unsigned)(unsigned short)q8[j] << 16);
            ks[s][c+j] = __uint_as_float((unsigned)(unsigned short)k8[j] << 16);
            vs[s][c+j] = __uint_as_float((unsigned)(unsigned short)v8[j] << 16);
        }
    }
    __syncthreads();
    if (t < SEQ_*SEQ_) {
        int qi = t / SEQ_, kj = t % SEQ_;
        float s = 0.f;
        #pragma unroll
        for (int d = 0; d < HD_; d++) s += qs[qi][d] * ks[kj][d];
        att[qi][kj] = s * 0.125f;
    }
    __syncthreads();
    if (t < SEQ_) {
        float mx = -1e30f;
        #pragma unroll
        for (int j = 0; j < SEQ_; j++) mx = fmaxf(mx, att[t][j]);
        float e[SEQ_]; float sum = 0.f;
        #pragma unroll
        for (int j = 0; j < SEQ_; j++) { e[j] = expf(att[t][j] - mx); sum += e[j]; }
        float inv = 1.f / sum;
        #pragma unroll
        for (int j = 0; j < SEQ_; j++) att[t][j] = e[j] * inv;
    }
    __syncthreads();
    for (int i = t; i < SEQ_*HD_; i += 256) {
        int s = i / HD_, d = i % HD_;
        float acc = 0.f;
        #pragma unroll
        for (int j = 0; j < SEQ_; j++) acc += att[s][j] * vs[j][d];
        o[(size_t)(cbb*SEQ_ + s) * 768 + hh*64 + d] = __float2bfloat16(acc);
    }
}

// ---------------- logits ----------------
__global__ __launch_bounds__(256) void k_logits(const __hip_bfloat16* __restrict__ hfin,
                                                const float* __restrict__ Wout,
                                                const float* __restrict__ bout,
                                                float* __restrict__ logits, int cb) {
    __shared__ float red[3][256];
    int blk = blockIdx.x;
    int t = threadIdx.x;
    const __hip_bfloat16* row = hfin + (size_t)blk * SEQ_ * E_;
    float a0 = 0.f, a1 = 0.f, a2 = 0.f;
    for (int e = t; e < SEQ_*E_; e += 256) {
        float x = __bfloat162float(row[e]);
        a0 += x * Wout[e*3 + 0]; a1 += x * Wout[e*3 + 1]; a2 += x * Wout[e*3 + 2];
    }
    red[0][t] = a0; red[1][t] = a1; red[2][t] = a2;
    __syncthreads();
    for (int o = 128; o > 0; o >>= 1) {
        if (t < o) { red[0][t] += red[0][t+o]; red[1][t] += red[1][t+o]; red[2][t] += red[2][t+o]; }
        __syncthreads();
    }
    if (t < 3) logits[((size_t)cb*B_ + blk)*3 + t] = red[t][0] + bout[t];
}

// ---------------- greedy matching: ONE wave, lazy-rescan row-cache ----------------
// Cached per-row min keys become LOWER BOUNDS as columns die. A stale key can only
// win the argmin if <= true global min, so: validate winner's column; if dead,
// cooperatively rescan just that row (64 lanes x 2 cols from LDS) and retry.
// Key = (costbits<<14)|(r*128+c) reproduces the reference argsort tie-break exactly.
__global__ __launch_bounds__(64) void k_match(const float* __restrict__ logits,
                                              const float* __restrict__ targets,
                                              float* __restrict__ losses) {
    __shared__ float cst[128 * 129];       // pad 129: bank (r+c)%32, 2-way max
    __shared__ float tg[128][3];
    __shared__ int mrow[128];
    int cl = blockIdx.x, lane = threadIdx.x;
    int lidx = cl + 1;
    for (int j = lane; j < 128; j += 64) {
        const float* tp = &targets[((size_t)j*L_ + (L_ - lidx)) * 3];
        tg[j][0] = tp[0]; tg[j][1] = tp[1]; tg[j][2] = tp[2];
    }
    __syncthreads();
    u64 kc[2];
    #pragma unroll
    for (int hh = 0; hh < 2; hh++) {
        int r = lane + hh*64;
        const float* lg = &logits[(cl*B_ + r) * 3];
        float l0 = lg[0], l1 = lg[1], l2 = lg[2];
        u64 best = ~0ull;
        for (int c = 0; c < 128; c++) {
            float d0 = l0 - tg[c][0], d1 = l1 - tg[c][1], d2 = l2 - tg[c][2];
            float cc = sqrtf(d0*d0 + d1*d1 + d2*d2 + 1e-12f);
            cst[r*129 + c] = cc;
            u64 key = ((u64)__float_as_uint(cc) << 14) | (unsigned)(r*128 + c);
            best = key < best ? key : best;
        }
        kc[hh] = best;
    }
    __syncthreads();                       // all rows of cst visible to all lanes
    u64 dead0 = 0, dead1 = 0;
    int done = 0;
    for (int trip = 0; trip < 16640 && done < 128; trip++) {
        u64 b = kc[0] < kc[1] ? kc[0] : kc[1];
        #pragma unroll
        for (int o = 32; o > 0; o >>= 1) {
            u64 x = __shfl_xor(b, o, 64);
            b = x < b ? x : b;
        }
        unsigned e  = (unsigned)b & 0x3fffu;
        unsigned wi = e >> 7, wj = e & 127;
        bool isDead = (((wj < 64) ? (dead0 >> wj) : (dead1 >> (wj - 64))) & 1ull) != 0;
        if (!isDead) {                     // wave-uniform branch
            if ((wi & 63u) == (unsigned)lane) {
                mrow[wi] = (int)wj;
                kc[wi >> 6] = ~0ull;
            }
            if (wj < 64) dead0 |= 1ull << wj; else dead1 |= 1ull << (wj - 64);
            done++;
        } else {                           // stale winner: rescan row wi cooperatively
            float c0 = cst[wi*129 + lane];
            float c1 = cst[wi*129 + lane + 64];
            bool d0b = ((dead0 >> lane) & 1ull) != 0;
            bool d1b = ((dead1 >> lane) & 1ull) != 0;
            u64 k0 = d0b ? ~0ull : (((u64)__float_as_uint(c0) << 14) | (unsigned)(wi*128 + lane));
            u64 k1 = d1b ? ~0ull : (((u64)__float_as_uint(c1) << 14) | (unsigned)(wi*128 + lane + 64));
            u64 nb = k0 < k1 ? k0 : k1;
            #pragma unroll
            for (int o = 32; o > 0; o >>= 1) {
                u64 x = __shfl_xor(nb, o, 64);
                nb = x < nb ? x : nb;
            }
            if ((wi & 63u) == (unsigned)lane) kc[wi >> 6] = nb;
        }
    }
    __syncthreads();
    float a = 0.f;
    #pragma unroll
    for (int hh = 0; hh < 2; hh++) {
        int r = lane + hh*64;
        const float* lg = &logits[(cl*B_ + mrow[r]) * 3];
        float d0 = lg[0]-tg[r][0], d1 = lg[1]-tg[r][1], d2 = lg[2]-tg[r][2];
        a += d0*d0 + d1*d1 + d2*d2;
    }
    #pragma unroll
    for (int o = 32; o > 0; o >>= 1) a += __shfl_xor(a, o, 64);
    if (lane == 0) losses[cl] = a * (1.0f / (B_*3));
}

__global__ void k_final(const float* __restrict__ losses, float* __restrict__ out) {
    float s = 0.f;
    for (int i = 0; i < 15; i++) s += losses[i];
    out[0] = s * (1.0f / 15.0f);
}

extern "C" void kernel_launch(void* const* d_in, const int* in_sizes, int n_in,
                              void* d_out, int out_size, void* d_ws, size_t ws_size,
                              hipStream_t stream) {
    (void)in_sizes; (void)n_in; (void)out_size;
    const float* X       = (const float*)d_in[0];
    const float* targets = (const float*)d_in[1];
    const float* omegas  = (const float*)d_in[2];
    const float* phases  = (const float*)d_in[3];
    const int*   perms   = (const int*)d_in[4];
    const float* Wq  = (const float*)d_in[5];
    const float* bq  = (const float*)d_in[6];
    const float* Wk  = (const float*)d_in[7];
    const float* bk  = (const float*)d_in[8];
    const float* Wv  = (const float*)d_in[9];
    const float* bv  = (const float*)d_in[10];
    const float* Wo  = (const float*)d_in[11];
    const float* bo  = (const float*)d_in[12];
    const float* ln1g = (const float*)d_in[13];
    const float* ln1b = (const float*)d_in[14];
    const float* ln2g = (const float*)d_in[15];
    const float* ln2b = (const float*)d_in[16];
    const float* W1  = (const float*)d_in[17];
    const float* b1f = (const float*)d_in[18];
    const float* W2  = (const float*)d_in[19];
    const float* b2f = (const float*)d_in[20];
    const float* lnfg = (const float*)d_in[21];
    const float* lnfb = (const float*)d_in[22];
    const float* Wout = (const float*)d_in[23];
    const float* bout = (const float*)d_in[24];

    // ws_size constant across calls -> branches are call-invariant (graph-safe).
    // FULL : M=23040 single pass, per-layer cvt (6 launches), 1-layer wl  (~262 MB)
    // MID  : M=7680 x3 passes, all-layer wl hoisted (6 cvt launches)      (~168 MB)
    // SMALL: M=7680 x3 passes, per-layer cvt (18 launches)                (~97 MB)
    int CL; bool hoist;
    if (ws_size >= 263000000ull)      { CL = 15; hoist = false; }
    else if (ws_size >= 169000000ull) { CL = 5;  hoist = true;  }
    else                              { CL = 5;  hoist = false; }
    int M = CL * B_ * SEQ_;
    bool perLayerCvt = (CL == 15) || !hoist;

    char* wsb = (char*)d_ws;
    size_t off = 0;
    auto alloc = [&](size_t bytes) {
        char* p = wsb + off;
        off += (bytes + 255) & ~(size_t)255;
        return p;
    };
    float*          x      = (float*)alloc((size_t)M*E_*4);
    __hip_bfloat16* h      = (__hip_bfloat16*)alloc((size_t)M*E_*2);
    __hip_bfloat16* qkvh   = (__hip_bfloat16*)alloc((size_t)M*3072*2);  // qkv(2304) | ffn hidden(3072)
    __hip_bfloat16* wl     = (__hip_bfloat16*)alloc((hoist ? 6 : 1) * (size_t)WLS*2);
    float*          bqkv   = (float*)alloc((hoist ? 6 : 1) * (size_t)BQS*4);
    float*          logits = (float*)alloc(23040);
    float*          losses = (float*)alloc(64);

    if (hoist)
        k_cvt<<<6*6913, 256, 0, stream>>>(Wq, Wk, Wv, Wo, W1, W2, bq, bk, bv, wl, bqkv, 0);

    dim3 gQKV(2304/128, M/128);
    dim3 gF1 (3072/128, M/128);
    dim3 gN64(768/64,   M/128);
    dim3 gLN (M/4);

    for (int cb = 0; cb < 15; cb += CL) {
        k_x0<<<(M*E_)/256, 256, 0, stream>>>(X, targets, perms, omegas, phases, x, cb, M);
        for (int l = 0; l < NL_; l++) {
            __hip_bfloat16* wlp = hoist ? wl + (size_t)l*WLS : wl;
            float*          bqp = hoist ? bqkv + l*BQS : bqkv;
            if (perLayerCvt)
                k_cvt<<<6913, 256, 0, stream>>>(Wq, Wk, Wv, Wo, W1, W2, bq, bk, bv, wlp, bqp, l);
            k_ln<<<gLN, 256, 0, stream>>>(x, ln1g + l*E_, ln1b + l*E_, h);
            k_gemm_t<128><<<gQKV, 256, 0, stream>>>(h, wlp, bqp, qkvh, 768, 768, 2304, 1);
            k_attn<<<CL*B_*H_, 256, 0, stream>>>(qkvh, h);
            k_gemm_t<64><<<gN64, 256, 0, stream>>>(h, wlp + 1769472, bo + l*E_, x,
                                                   768, 768, 768, 2);
            k_ln<<<gLN, 256, 0, stream>>>(x, ln2g + l*E_, ln2b + l*E_, h);
            k_gemm_t<128><<<gF1, 256, 0, stream>>>(h, wlp + 2359296, b1f + l*3072, qkvh,
                                                   768, 768, 3072, 1|4);
            k_gemm_t<64><<<gN64, 256, 0, stream>>>(qkvh, wlp + 4718592, b2f + l*E_, x,
                                                   3072, 3072, 768, 2);
        }
        k_ln<<<gLN, 256, 0, stream>>>(x, lnfg, lnfb, h);
        k_logits<<<CL*B_, 256, 0, stream>>>(h, Wout, bout, logits, cb);
    }
    k_match<<<15, 64, 0, stream>>>(logits, targets, losses);
    k_final<<<1, 1, 0, stream>>>(losses, (float*)d_out);
}